// Round 3
// baseline (209.884 us; speedup 1.0000x reference)
//
#include <hip/hip_runtime.h>
#include <hip/hip_bf16.h>
#include <math.h>

#define RR 1024
#define BB 16
#define DD 1024
#define K_ACTIVE 20

// native clang vector type — accepted by __builtin_nontemporal_store
typedef float vfloat4 __attribute__((ext_vector_type(4)));

// ---------------------------------------------------------------------------
// Kernel 1: per (r,b) pair compute dot(H[r,b,:], w) and sumsq(msg[r,b,:]).
// One wave per pair; ALL 12 float4 loads staged into named registers before
// any use, so the compiler issues them back-to-back (12 in-flight vmem ops
// per wave) instead of the 32-VGPR issue/wait/reuse serialization seen in R1.
// ---------------------------------------------------------------------------
__global__ __launch_bounds__(256) void score_kernel(
    const float* __restrict__ H, const float* __restrict__ msg,
    const float* __restrict__ w, const float* __restrict__ theta,
    const float* __restrict__ refr, const float* __restrict__ fb,
    float* __restrict__ adj_out)
{
    const int wave = threadIdx.x >> 6;
    const int lane = threadIdx.x & 63;
    const int pair = blockIdx.x * 4 + wave;   // pair = r*BB + b
    const int r = pair >> 4;
    const int b = pair & 15;

    const vfloat4* __restrict__ H4 = (const vfloat4*)(H + (size_t)pair * DD);
    const vfloat4* __restrict__ M4 = (const vfloat4*)(msg + (size_t)pair * DD);
    const vfloat4* __restrict__ W4 = (const vfloat4*)w;

    // Stage all loads first: 12 independent global_load_dwordx4 in flight.
    const vfloat4 h0 = H4[lane],       h1 = H4[lane + 64];
    const vfloat4 h2 = H4[lane + 128], h3 = H4[lane + 192];
    const vfloat4 m0 = M4[lane],       m1 = M4[lane + 64];
    const vfloat4 m2 = M4[lane + 128], m3 = M4[lane + 192];
    const vfloat4 w0 = W4[lane],       w1 = W4[lane + 64];
    const vfloat4 w2 = W4[lane + 128], w3 = W4[lane + 192];

    float dot = h0.x * w0.x + h0.y * w0.y + h0.z * w0.z + h0.w * w0.w;
    dot += h1.x * w1.x + h1.y * w1.y + h1.z * w1.z + h1.w * w1.w;
    dot += h2.x * w2.x + h2.y * w2.y + h2.z * w2.z + h2.w * w2.w;
    dot += h3.x * w3.x + h3.y * w3.y + h3.z * w3.z + h3.w * w3.w;

    float ss = m0.x * m0.x + m0.y * m0.y + m0.z * m0.z + m0.w * m0.w;
    ss += m1.x * m1.x + m1.y * m1.y + m1.z * m1.z + m1.w * m1.w;
    ss += m2.x * m2.x + m2.y * m2.y + m2.z * m2.z + m2.w * m2.w;
    ss += m3.x * m3.x + m3.y * m3.y + m3.z * m3.z + m3.w * m3.w;

#pragma unroll
    for (int off = 32; off > 0; off >>= 1) {
        dot += __shfl_down(dot, off);
        ss  += __shfl_down(ss, off);
    }
    if (lane == 0) {
        const float fb_mag = sqrtf(ss);
        const float fb_new = 0.9f * fb[b * RR + r] + 0.1f * fb_mag;
        adj_out[b * RR + r] = dot - theta[r] - refr[b * RR + r] - 0.5f * fb_new;
    }
}

// ---------------------------------------------------------------------------
// Kernel 2: greedy hex NMS — ONE WAVE per batch (16 blocks x 64 threads).
// Single-wave blocks make __syncthreads trivial; nbrs preloaded into LDS;
// the 7 suppression writes happen in parallel on lanes 0..6.
// Equivalent to the reference scan over argsort(-adj): iterated argmax over
// non-suppressed entries, tie -> lowest index (stable sort order).
// ---------------------------------------------------------------------------
__global__ __launch_bounds__(64) void nms_kernel(
    const float* __restrict__ adj, const int* __restrict__ nbrs,
    float* __restrict__ hard)
{
    __shared__ float val[RR];
    __shared__ int   nb[RR * 6];
    __shared__ unsigned char sel[RR];

    const int b = blockIdx.x;
    const int lane = threadIdx.x;   // 0..63

#pragma unroll
    for (int j = 0; j < 16; ++j) {
        const int i = lane + 64 * j;
        val[i] = adj[b * RR + i];
        sel[i] = 0;
    }
    // nbrs: 1024*6 ints = 1536 int4
    const int4* nb4g = (const int4*)nbrs;
    int4* nb4s = (int4*)nb;
#pragma unroll
    for (int j = 0; j < 24; ++j)
        nb4s[lane + 64 * j] = nb4g[lane + 64 * j];
    __syncthreads();

    for (int it = 0; it < K_ACTIVE; ++it) {
        float m = -INFINITY;
        int mi = RR;
#pragma unroll
        for (int j = 0; j < 16; ++j) {
            const int i = lane + 64 * j;
            const float v = val[i];
            if (v > m || (v == m && i < mi)) { m = v; mi = i; }
        }
#pragma unroll
        for (int off = 32; off > 0; off >>= 1) {
            const float ov = __shfl_down(m, off);
            const int   oi = __shfl_down(mi, off);
            if (ov > m || (ov == m && oi < mi)) { m = ov; mi = oi; }
        }
        const int   bi = __shfl(mi, 0);
        const float bm = __shfl(m, 0);
        if (bm > -INFINITY) {
            if (lane == 0) { sel[bi] = 1; val[bi] = -INFINITY; }
            if (lane < 6)  { val[nb[bi * 6 + lane]] = -INFINITY; }
        }
        __syncthreads();
    }

#pragma unroll
    for (int j = 0; j < 16; ++j) {
        const int i = lane + 64 * j;
        hard[b * RR + i] = sel[i] ? 1.0f : 0.0f;
    }
}

// ---------------------------------------------------------------------------
// Kernel 3: Hs[r,b,:] = hard[b,r] ? H[r,b,:] : 0. One wave per pair, 4
// float4 nontemporal stores per lane (output is write-once, never re-read).
// Gated-off rows (~98%) write zeros without reading H.
// ---------------------------------------------------------------------------
__global__ __launch_bounds__(256) void gate_kernel(
    const float* __restrict__ H, const float* __restrict__ hard,
    float* __restrict__ Hs)
{
    const int wave = threadIdx.x >> 6;
    const int lane = threadIdx.x & 63;
    const int pair = blockIdx.x * 4 + wave;   // pair = r*BB + b
    const int r = pair >> 4;
    const int b = pair & 15;
    const float g = hard[b * RR + r];

    vfloat4* out4 = (vfloat4*)(Hs + (size_t)pair * DD);
    if (g != 0.0f) {
        const vfloat4* H4 = (const vfloat4*)(H + (size_t)pair * DD);
        const vfloat4 v0 = H4[lane],       v1 = H4[lane + 64];
        const vfloat4 v2 = H4[lane + 128], v3 = H4[lane + 192];
        __builtin_nontemporal_store(v0, &out4[lane]);
        __builtin_nontemporal_store(v1, &out4[lane + 64]);
        __builtin_nontemporal_store(v2, &out4[lane + 128]);
        __builtin_nontemporal_store(v3, &out4[lane + 192]);
    } else {
        const vfloat4 z = {0.f, 0.f, 0.f, 0.f};
        __builtin_nontemporal_store(z, &out4[lane]);
        __builtin_nontemporal_store(z, &out4[lane + 64]);
        __builtin_nontemporal_store(z, &out4[lane + 128]);
        __builtin_nontemporal_store(z, &out4[lane + 192]);
    }
}

extern "C" void kernel_launch(void* const* d_in, const int* in_sizes, int n_in,
                              void* d_out, int out_size, void* d_ws, size_t ws_size,
                              hipStream_t stream) {
    const float* H     = (const float*)d_in[0];   // [R,B,D]
    const float* msg   = (const float*)d_in[1];   // [R,B,D]
    const float* w     = (const float*)d_in[2];   // [D]
    const float* theta = (const float*)d_in[3];   // [R]
    const float* refr  = (const float*)d_in[4];   // [B,R]
    const float* fb    = (const float*)d_in[5];   // [B,R]
    const int*   nbrs  = (const int*)d_in[6];     // [R,6]

    float* out  = (float*)d_out;
    float* Hs   = out;                                   // [R,B,D]
    float* hard = out + (size_t)RR * BB * DD;            // [B,R]
    float* adj  = hard + (size_t)BB * RR;                // [B,R]

    score_kernel<<<RR * BB / 4, 256, 0, stream>>>(H, msg, w, theta, refr, fb, adj);
    nms_kernel<<<BB, 64, 0, stream>>>(adj, nbrs, hard);
    gate_kernel<<<RR * BB / 4, 256, 0, stream>>>(H, hard, Hs);
}